// Round 4
// baseline (207.302 us; speedup 1.0000x reference)
//
#include <hip/hip_runtime.h>
#include <stdint.h>

#define NROWS 16384
#define SPLITN 100
#define IDIM 128
#define NH 4
#define PD 64
#define ROWLEN (SPLITN * IDIM)   // 12800
#define ODIM (NH * PD)           // 256

typedef float f32x4 __attribute__((ext_vector_type(4)));
typedef short s16x8 __attribute__((ext_vector_type(8)));
typedef unsigned short u16x8 __attribute__((ext_vector_type(8)));

__device__ __forceinline__ unsigned short f32_to_bf16(float f) {
  uint32_t u = __float_as_uint(f);
  u += 0x7FFFu + ((u >> 16) & 1u);   // RNE
  return (unsigned short)(u >> 16);
}

#if __has_builtin(__builtin_amdgcn_exp2f)
__device__ __forceinline__ float fexp2(float x) { return __builtin_amdgcn_exp2f(x); }
#else
__device__ __forceinline__ float fexp2(float x) { return exp2f(x); }
#endif

template <int IMM>
__device__ __forceinline__ float swz_f(float v) {
  return __int_as_float(__builtin_amdgcn_ds_swizzle(__float_as_int(v), IMM));
}

// ---------- prep (merged): blocks 0..127 pack W->bf16 B-frags; block 128 does wq ----------
// frag f = ((h*4+kb)*4+of); lane l elem j holds W[h][kb*32+(l>>4)*8+j][of*16+(l&15)]
__global__ void prep(const float* __restrict__ W, const float* __restrict__ q,
                     float* __restrict__ wq, unsigned short* __restrict__ Wp) {
  if (blockIdx.x < 128) {
    int flat = blockIdx.x * 256 + threadIdx.x;  // 64 frags * 512
    int f = flat >> 9;
    int rem = flat & 511;
    int l = rem >> 3, j = rem & 7;
    int of = f & 3, kb = (f >> 2) & 3, h = f >> 4;
    int k = kb * 32 + (l >> 4) * 8 + j;
    int o = of * 16 + (l & 15);
    Wp[flat] = f32_to_bf16(W[(size_t)(h * IDIM + k) * PD + o]);
  } else {
    for (int item = threadIdx.x; item < NH * IDIM; item += 256) {
      int h = item >> 7, i = item & (IDIM - 1);
      const float* wrow = W + (size_t)(h * IDIM + i) * PD;
      const float* qh = q + h * PD;
      float s = 0.f;
#pragma unroll 8
      for (int o = 0; o < PD; ++o) s = __builtin_fmaf(wrow[o], qh[o], s);
      wq[item] = s;
    }
  }
}

// ---------- k1: fused score + online softmax + weighted pooling ----------
// ONE ROW PER BLOCK: 4 waves x 4 groups = 16 interleaved streams, stream
// k=(w*4+g) handles s = k + 16t. Each block-iteration touches one contiguous
// 8 KB chunk of the row -> 4x fewer concurrent DRAM row-streams device-wide.
// Nontemporal loads: x is read exactly once, skip L2 allocation.
__global__ __launch_bounds__(256) void k1(const float* __restrict__ x,
                                          const float* __restrict__ wq,
                                          unsigned short* __restrict__ ybf) {
  const int w = threadIdx.x >> 6;     // wave 0..3
  const int lane = threadIdx.x & 63;
  const int g = lane >> 4;            // group within wave
  const int li = lane & 15;           // i-octet index
  const int strm = w * 4 + g;         // 0..15
  const int row = blockIdx.x;
  const float* p = x + (size_t)row * ROWLEN + strm * IDIM + li * 8;

  __shared__ float mLb[4][NH];
  __shared__ float lb[4][NH];
  __shared__ float yb[4][NH][128];

  float wqr[NH][8];
#pragma unroll
  for (int h = 0; h < NH; ++h) {
    f32x4 a = *(const f32x4*)(wq + h * IDIM + li * 8);
    f32x4 b = *(const f32x4*)(wq + h * IDIM + li * 8 + 4);
#pragma unroll
    for (int j = 0; j < 4; ++j) { wqr[h][j] = a[j]; wqr[h][4 + j] = b[j]; }
  }

  float y[NH][8];
  float m[NH], lsum[NH], mL[NH];
#pragma unroll
  for (int h = 0; h < NH; ++h) {
    m[h] = -INFINITY; mL[h] = -INFINITY; lsum[h] = 0.f;
#pragma unroll
    for (int j = 0; j < 8; ++j) y[h][j] = 0.f;
  }
  const float L2E = 1.44269504088896340736f;

  // s = strm + 16t <= 99  ->  wave 0 (strm<4) runs 7 iters, others 6
  const int niter = (w == 0) ? 7 : 6;
  for (int t = 0; t < niter; ++t) {
    f32x4 xa = __builtin_nontemporal_load((const f32x4*)p);
    f32x4 xb = __builtin_nontemporal_load((const f32x4*)(p + 4));
    p += 16 * IDIM;

    float xv[8];
#pragma unroll
    for (int j = 0; j < 4; ++j) { xv[j] = xa[j]; xv[4 + j] = xb[j]; }

    float part[NH];
#pragma unroll
    for (int h = 0; h < NH; ++h) {
      float pp = xv[0] * wqr[h][0];
#pragma unroll
      for (int j = 1; j < 8; ++j) pp = __builtin_fmaf(xv[j], wqr[h][j], pp);
      part[h] = pp;
    }
    // reduce over the 16 lanes of this group (xor 1,2,4,8)
#pragma unroll
    for (int h = 0; h < NH; ++h) {
      part[h] += swz_f<0x041F>(part[h]);
      part[h] += swz_f<0x081F>(part[h]);
      part[h] += swz_f<0x101F>(part[h]);
      part[h] += swz_f<0x201F>(part[h]);
    }
#pragma unroll
    for (int h = 0; h < NH; ++h) {
      float sc = part[h];
      sc = sc > 0.f ? sc : 0.2f * sc;      // leaky_relu
      if (sc > m[h] + 8.0f) {              // defer-max rescale (rare)
        float scale = fexp2(mL[h] - sc * L2E);  // exp2(-inf)=0 on first hit
        lsum[h] *= scale;
#pragma unroll
        for (int j = 0; j < 8; ++j) y[h][j] *= scale;
        m[h] = sc; mL[h] = sc * L2E;
      }
      float wgt = fexp2(__builtin_fmaf(sc, L2E, -mL[h]));
      lsum[h] += wgt;
#pragma unroll
      for (int j = 0; j < 8; ++j) y[h][j] = __builtin_fmaf(wgt, xv[j], y[h][j]);
    }
  }

  // merge the wave's 4 group-streams (xor 16 then 32)
#pragma unroll
  for (int st = 16; st <= 32; st <<= 1) {
#pragma unroll
    for (int h = 0; h < NH; ++h) {
      float mo = __shfl_xor(m[h], st, 64);
      float lo = __shfl_xor(lsum[h], st, 64);
      float mn = fmaxf(m[h], mo);
      float ea = fexp2((m[h] - mn) * L2E);
      float eb = fexp2((mo - mn) * L2E);
      lsum[h] = lsum[h] * ea + lo * eb;
#pragma unroll
      for (int j = 0; j < 8; ++j) {
        float yo = __shfl_xor(y[h][j], st, 64);
        y[h][j] = y[h][j] * ea + yo * eb;
      }
      m[h] = mn;
    }
  }

  // publish per-wave state to LDS
  if (lane < 16) {
#pragma unroll
    for (int h = 0; h < NH; ++h) {
      *(f32x4*)&yb[w][h][li * 8]     = (f32x4){y[h][0], y[h][1], y[h][2], y[h][3]};
      *(f32x4*)&yb[w][h][li * 8 + 4] = (f32x4){y[h][4], y[h][5], y[h][6], y[h][7]};
    }
    if (lane == 0) {
#pragma unroll
      for (int h = 0; h < NH; ++h) { mLb[w][h] = m[h] * L2E; lb[w][h] = lsum[h]; }
    }
  }
  __syncthreads();

  // cross-wave flash-merge: wave w handles head h=w; lanes 0..15 active
  if (lane < 16) {
    const int h = w;
    float mm = fmaxf(fmaxf(mLb[0][h], mLb[1][h]), fmaxf(mLb[2][h], mLb[3][h]));
    float ls = 0.f;
    float yj[8];
#pragma unroll
    for (int j = 0; j < 8; ++j) yj[j] = 0.f;
#pragma unroll
    for (int ww = 0; ww < 4; ++ww) {
      float e = fexp2(mLb[ww][h] - mm);
      ls = __builtin_fmaf(lb[ww][h], e, ls);
      f32x4 ya = *(const f32x4*)&yb[ww][h][li * 8];
      f32x4 yc = *(const f32x4*)&yb[ww][h][li * 8 + 4];
#pragma unroll
      for (int j = 0; j < 4; ++j) {
        yj[j] = __builtin_fmaf(ya[j], e, yj[j]);
        yj[4 + j] = __builtin_fmaf(yc[j], e, yj[4 + j]);
      }
    }
    float inv = 1.0f / ls;
    u16x8 pk;
#pragma unroll
    for (int j = 0; j < 8; ++j) pk[j] = f32_to_bf16(yj[j] * inv);
    *(u16x8*)(ybf + (size_t)row * 512 + h * 128 + li * 8) = pk;
  }
}

// ---------- k2: pooled = y_bf16 @ W_bf16 (per head) -> fp32 out ----------
// Primary path: ybf lives in d_ws, out is d_out -> no aliasing anywhere.
__global__ __launch_bounds__(256) void k2(const unsigned short* ybf,
                                          const unsigned short* __restrict__ Wp,
                                          float* out) {
  const int h = threadIdx.x >> 6;   // wave -> head
  const int l = threadIdx.x & 63;
  const int rowb = blockIdx.x * 32;

  s16x8 Bf[4][4];
#pragma unroll
  for (int kb = 0; kb < 4; ++kb)
#pragma unroll
    for (int of = 0; of < 4; ++of)
      Bf[kb][of] = *(const s16x8*)(Wp + (size_t)(((h * 4 + kb) * 4 + of) * 512 + l * 8));

  s16x8 Af[2][4];
#pragma unroll
  for (int mf = 0; mf < 2; ++mf)
#pragma unroll
    for (int kb = 0; kb < 4; ++kb) {
      int r = rowb + mf * 16 + (l & 15);
      Af[mf][kb] = *(const s16x8*)(ybf + (size_t)r * 512 + h * 128 + kb * 32 + (l >> 4) * 8);
    }

  f32x4 acc[2][4];
#pragma unroll
  for (int mf = 0; mf < 2; ++mf)
#pragma unroll
    for (int of = 0; of < 4; ++of) acc[mf][of] = (f32x4){0.f, 0.f, 0.f, 0.f};

#pragma unroll
  for (int kb = 0; kb < 4; ++kb)
#pragma unroll
    for (int mf = 0; mf < 2; ++mf)
#pragma unroll
      for (int of = 0; of < 4; ++of)
        acc[mf][of] = __builtin_amdgcn_mfma_f32_16x16x32_bf16(Af[mf][kb], Bf[kb][of],
                                                              acc[mf][of], 0, 0, 0);

#pragma unroll
  for (int mf = 0; mf < 2; ++mf)
#pragma unroll
    for (int of = 0; of < 4; ++of)
#pragma unroll
      for (int reg = 0; reg < 4; ++reg) {
        int r = rowb + mf * 16 + (l >> 4) * 4 + reg;
        int o = of * 16 + (l & 15);
        out[(size_t)r * ODIM + h * PD + o] = acc[mf][of][reg];
      }
}

extern "C" void kernel_launch(void* const* d_in, const int* in_sizes, int n_in,
                              void* d_out, int out_size, void* d_ws, size_t ws_size,
                              hipStream_t stream) {
  const float* x = (const float*)d_in[0];
  const float* W = (const float*)d_in[1];
  const float* q = (const float*)d_in[2];
  float* out = (float*)d_out;
  float* wq = (float*)d_ws;                                     // 2 KB
  unsigned short* Wp = (unsigned short*)((char*)d_ws + 2048);   // 64 KB

  // y staging: clean (non-aliased) home in d_ws at +1 MB (proven in R3).
  const size_t YOFF = (size_t)1 << 20;
  const size_t YBYTES = (size_t)NROWS * 512 * sizeof(unsigned short);  // 16.8 MB
  unsigned short* ybf = (ws_size >= YOFF + YBYTES)
                            ? (unsigned short*)((char*)d_ws + YOFF)
                            : (unsigned short*)d_out;

  prep<<<129, 256, 0, stream>>>(W, q, wq, Wp);
  k1<<<NROWS, 256, 0, stream>>>(x, wq, ybf);
  k2<<<NROWS / 32, 256, 0, stream>>>(ybf, Wp, out);
}

// Round 5
// 167.217 us; speedup vs baseline: 1.2397x; 1.2397x over previous
//
#include <hip/hip_runtime.h>
#include <stdint.h>

#define NROWS 16384
#define SPLITN 100
#define IDIM 128
#define NH 4
#define PD 64
#define ROWLEN (SPLITN * IDIM)   // 12800
#define ODIM (NH * PD)           // 256
#define RPB 16                   // rows (waves) per block

typedef float f32x4 __attribute__((ext_vector_type(4)));
typedef short s16x8 __attribute__((ext_vector_type(8)));
typedef unsigned short u16x8 __attribute__((ext_vector_type(8)));

__device__ __forceinline__ unsigned short f32_to_bf16(float f) {
  uint32_t u = __float_as_uint(f);
  u += 0x7FFFu + ((u >> 16) & 1u);   // RNE
  return (unsigned short)(u >> 16);
}

#if __has_builtin(__builtin_amdgcn_exp2f)
__device__ __forceinline__ float fexp2(float x) { return __builtin_amdgcn_exp2f(x); }
#else
__device__ __forceinline__ float fexp2(float x) { return exp2f(x); }
#endif

template <int IMM>
__device__ __forceinline__ float swz_f(float v) {
  return __int_as_float(__builtin_amdgcn_ds_swizzle(__float_as_int(v), IMM));
}

// ---------- prep (merged, proven R4): blocks 0..127 pack W->bf16 B-frags; block 128 wq ----------
// frag f = ((h*4+kb)*4+of); lane l elem j holds W[h][kb*32+(l>>4)*8+j][of*16+(l&15)]
__global__ void prep(const float* __restrict__ W, const float* __restrict__ q,
                     float* __restrict__ wq, unsigned short* __restrict__ Wp) {
  if (blockIdx.x < 128) {
    int flat = blockIdx.x * 256 + threadIdx.x;  // 64 frags * 512
    int f = flat >> 9;
    int rem = flat & 511;
    int l = rem >> 3, j = rem & 7;
    int of = f & 3, kb = (f >> 2) & 3, h = f >> 4;
    int k = kb * 32 + (l >> 4) * 8 + j;
    int o = of * 16 + (l & 15);
    Wp[flat] = f32_to_bf16(W[(size_t)(h * IDIM + k) * PD + o]);
  } else {
    for (int item = threadIdx.x; item < NH * IDIM; item += 256) {
      int h = item >> 7, i = item & (IDIM - 1);
      const float* wrow = W + (size_t)(h * IDIM + i) * PD;
      const float* qh = q + h * PD;
      float s = 0.f;
#pragma unroll 8
      for (int o = 0; o < PD; ++o) s = __builtin_fmaf(wrow[o], qh[o], s);
      wq[item] = s;
    }
  }
}

// ---------- k1: fully fused  score + online softmax + pooling + projection ----------
// 16 waves/block, wave w = row blockIdx*16+w, R1's proven stream pattern:
// 4 groups/wave, group g handles s=4t+g, wave reads contiguous 2 KB/iter, 25 iters.
// Epilogue: normalized y -> LDS (bf16, padded rows), waves 0..3 project head w
// via mfma_f32_16x16x32_bf16 against the prepacked Wp B-frags -> fp32 out.
__global__ __launch_bounds__(1024) void k1(const float* __restrict__ x,
                                           const float* __restrict__ wq,
                                           const unsigned short* __restrict__ Wp,
                                           float* __restrict__ out) {
  const int w = threadIdx.x >> 6;     // wave = row-in-block 0..15
  const int lane = threadIdx.x & 63;
  const int g = lane >> 4;            // s-stream
  const int li = lane & 15;           // i-octet index
  const int row = blockIdx.x * RPB + w;
  const float* pc = x + (size_t)row * ROWLEN + g * IDIM + li * 8;

  // [16 rows][4*128 + 8 pad] bf16 y tile (pad -> row stride 1040 B, banks +4/row)
  __shared__ unsigned short ybt[RPB][NH * IDIM + 8];

  float wqr[NH][8];
#pragma unroll
  for (int h = 0; h < NH; ++h) {
    f32x4 a = *(const f32x4*)(wq + h * IDIM + li * 8);
    f32x4 b = *(const f32x4*)(wq + h * IDIM + li * 8 + 4);
#pragma unroll
    for (int j = 0; j < 4; ++j) { wqr[h][j] = a[j]; wqr[h][4 + j] = b[j]; }
  }

  float y[NH][8];
  float m[NH], lsum[NH], mL[NH];
#pragma unroll
  for (int h = 0; h < NH; ++h) {
    m[h] = -INFINITY; mL[h] = -INFINITY; lsum[h] = 0.f;
#pragma unroll
    for (int j = 0; j < 8; ++j) y[h][j] = 0.f;
  }
  const float L2E = 1.44269504088896340736f;

  f32x4 xa = *(const f32x4*)pc;
  f32x4 xb = *(const f32x4*)(pc + 4);

  for (int it = 0; it < 25; ++it) {
    f32x4 na = {}, nb = {};
    const float* pn = pc + 4 * IDIM;
    if (it < 24) { na = *(const f32x4*)pn; nb = *(const f32x4*)(pn + 4); }

    float xv[8];
#pragma unroll
    for (int j = 0; j < 4; ++j) { xv[j] = xa[j]; xv[4 + j] = xb[j]; }

    float part[NH];
#pragma unroll
    for (int h = 0; h < NH; ++h) {
      float p = xv[0] * wqr[h][0];
#pragma unroll
      for (int j = 1; j < 8; ++j) p = __builtin_fmaf(xv[j], wqr[h][j], p);
      part[h] = p;
    }
#pragma unroll
    for (int h = 0; h < NH; ++h) {
      part[h] += swz_f<0x041F>(part[h]);
      part[h] += swz_f<0x081F>(part[h]);
      part[h] += swz_f<0x101F>(part[h]);
      part[h] += swz_f<0x201F>(part[h]);
    }
#pragma unroll
    for (int h = 0; h < NH; ++h) {
      float sc = part[h];
      sc = sc > 0.f ? sc : 0.2f * sc;      // leaky_relu
      if (sc > m[h] + 8.0f) {              // defer-max rescale (rare)
        float scale = fexp2(mL[h] - sc * L2E);  // exp2(-inf)=0 on first hit
        lsum[h] *= scale;
#pragma unroll
        for (int j = 0; j < 8; ++j) y[h][j] *= scale;
        m[h] = sc; mL[h] = sc * L2E;
      }
      float wt = fexp2(__builtin_fmaf(sc, L2E, -mL[h]));
      lsum[h] += wt;
#pragma unroll
      for (int j = 0; j < 8; ++j) y[h][j] = __builtin_fmaf(wt, xv[j], y[h][j]);
    }
    xa = na; xb = nb; pc = pn;
  }

  // flash-merge the 4 streams (xor 16 then 32) -> all lanes hold full-row state
#pragma unroll
  for (int st = 16; st <= 32; st <<= 1) {
#pragma unroll
    for (int h = 0; h < NH; ++h) {
      float mo = __shfl_xor(m[h], st, 64);
      float lo = __shfl_xor(lsum[h], st, 64);
      float mn = fmaxf(m[h], mo);
      float ea = fexp2((m[h] - mn) * L2E);
      float eb = fexp2((mo - mn) * L2E);
      lsum[h] = lsum[h] * ea + lo * eb;
#pragma unroll
      for (int j = 0; j < 8; ++j) {
        float yo = __shfl_xor(y[h][j], st, 64);
        y[h][j] = y[h][j] * ea + yo * eb;
      }
      m[h] = mn;
    }
  }

  // group g publishes head g (normalized, bf16) into the LDS y tile
  {
    float lg = lsum[0];
    float ys[8];
#pragma unroll
    for (int j = 0; j < 8; ++j) ys[j] = y[0][j];
#pragma unroll
    for (int h = 1; h < NH; ++h) {
      bool sel = (g == h);
      lg = sel ? lsum[h] : lg;
#pragma unroll
      for (int j = 0; j < 8; ++j) ys[j] = sel ? y[h][j] : ys[j];
    }
    float inv = 1.0f / lg;
    u16x8 pk;
#pragma unroll
    for (int j = 0; j < 8; ++j) pk[j] = f32_to_bf16(ys[j] * inv);
    *(u16x8*)&ybt[w][g * IDIM + li * 8] = pk;
  }
  __syncthreads();

  // projection: waves 0..3, wave h projects head h for all 16 rows
  if (w < NH) {
    const int h = w;
    const int l = lane;

    s16x8 Bf[4][4];
#pragma unroll
    for (int kb = 0; kb < 4; ++kb)
#pragma unroll
      for (int of = 0; of < 4; ++of)
        Bf[kb][of] = *(const s16x8*)(Wp + (size_t)(((h * 4 + kb) * 4 + of) * 512 + l * 8));

    s16x8 Af[4];
#pragma unroll
    for (int kb = 0; kb < 4; ++kb)
      Af[kb] = *(const s16x8*)&ybt[l & 15][h * IDIM + kb * 32 + (l >> 4) * 8];

    f32x4 acc[4];
#pragma unroll
    for (int of = 0; of < 4; ++of) acc[of] = (f32x4){0.f, 0.f, 0.f, 0.f};

#pragma unroll
    for (int kb = 0; kb < 4; ++kb)
#pragma unroll
      for (int of = 0; of < 4; ++of)
        acc[of] = __builtin_amdgcn_mfma_f32_16x16x32_bf16(Af[kb], Bf[kb][of],
                                                          acc[of], 0, 0, 0);

    const int rowb = blockIdx.x * RPB;
#pragma unroll
    for (int of = 0; of < 4; ++of)
#pragma unroll
      for (int reg = 0; reg < 4; ++reg) {
        int r = rowb + (l >> 4) * 4 + reg;
        int o = of * 16 + (l & 15);
        out[(size_t)r * ODIM + h * PD + o] = acc[of][reg];
      }
  }
}

extern "C" void kernel_launch(void* const* d_in, const int* in_sizes, int n_in,
                              void* d_out, int out_size, void* d_ws, size_t ws_size,
                              hipStream_t stream) {
  const float* x = (const float*)d_in[0];
  const float* W = (const float*)d_in[1];
  const float* q = (const float*)d_in[2];
  float* out = (float*)d_out;
  float* wq = (float*)d_ws;                                     // 2 KB
  unsigned short* Wp = (unsigned short*)((char*)d_ws + 2048);   // 64 KB

  prep<<<129, 256, 0, stream>>>(W, q, wq, Wp);
  k1<<<NROWS / RPB, 1024, 0, stream>>>(x, wq, Wp, out);
}